// Round 2
// baseline (252.392 us; speedup 1.0000x reference)
//
#include <hip/hip_runtime.h>

#define NLINKS 4096
#define VEC 16            // fvec4 per lane: 16 * 4 * 64 lanes = 4096

typedef float fvec4 __attribute__((ext_vector_type(4)));

constexpr float kPmax = 0.1f;
constexpr float kBudget = 100.0f;
constexpr int kGrid = 8;          // fixed tau grid evaluated in the load pass
constexpr int kFallbackIters = 8; // Illinois iters when tau is outside the grid

// clip(x,0,PMAX) in ONE VALU op: v_med3_f32
__device__ __forceinline__ float clip01(float x) {
  return __builtin_amdgcn_fmed3f(x, 0.0f, kPmax);
}

// Batched reduce: N independent sums share interleaved shuffle latency.
template <int N>
__device__ __forceinline__ void waveReduceSumN(float* x) {
#pragma unroll
  for (int m = 32; m >= 1; m >>= 1) {
    float t[N];
#pragma unroll
    for (int k = 0; k < N; ++k) t[k] = __shfl_xor(x[k], m, 64);
#pragma unroll
    for (int k = 0; k < N; ++k) x[k] += t[k];
  }
}
__device__ __forceinline__ float waveReduceMax(float x) {
#pragma unroll
  for (int m = 32; m >= 1; m >>= 1) x = fmaxf(x, __shfl_xor(x, m, 64));
  return x;
}

__device__ __forceinline__ void loadRow(const float* __restrict__ raw, int row,
                                        int lane, fvec4 (&v)[VEC]) {
  const fvec4* rp = (const fvec4*)(raw + (size_t)row * NLINKS);
#pragma unroll
  for (int j = 0; j < VEC; ++j) v[j] = __builtin_nontemporal_load(&rp[lane + 64 * j]);
}

// Per-row projection: identical arithmetic / op order to the 226 µs kernel
// (absmax must be unchanged). Only the scheduling around it changed.
__device__ __forceinline__ void processRow(const fvec4 (&v)[VEC],
                                           float* __restrict__ out, int row,
                                           int lane) {
  fvec4* op = (fvec4*)(out + (size_t)row * NLINKS);

  // tau grid: rows are ~N(0,1), n=4096 => tau ~= 0.641 +- 0.02. Grid spans
  // ~[-9sigma,+12sigma]; outside -> Illinois fallback (correct, ~never taken).
  const float pts[kGrid] = {0.45f, 0.52f, 0.58f, 0.62f, 0.66f, 0.70f, 0.78f, 0.90f};

  // Single pass: row max, g(0)=fs, and g(pts[i]) for all 8 grid points (ILP).
  float mx = -1e30f;
  float s[kGrid + 1];
#pragma unroll
  for (int k = 0; k <= kGrid; ++k) s[k] = 0.f;
#pragma unroll
  for (int j = 0; j < VEC; ++j) {
#pragma unroll
    for (int c = 0; c < 4; ++c) {
      const float x = v[j][c];
      mx = fmaxf(mx, x);
      s[0] += clip01(x);
#pragma unroll
      for (int i = 0; i < kGrid; ++i) s[i + 1] += clip01(x - pts[i]);
    }
  }
  waveReduceSumN<kGrid + 1>(s);
  mx = waveReduceMax(mx);
  const float fs = s[0];

  if (fs <= kBudget) {  // feasible: clip only (wave-uniform branch)
#pragma unroll
    for (int j = 0; j < VEC; ++j) {
      fvec4 o;
#pragma unroll
      for (int c = 0; c < 4; ++c) o[c] = clip01(v[j][c]);
      __builtin_nontemporal_store(o, &op[lane + 64 * j]);
    }
    return;
  }

  // Select bracketing segment. g is decreasing: g(0)=fs>B, g(mx)=0.
  float a = 0.f, ga = fs, b = mx, gb = 0.f;
  bool need_iter = true;
  if (s[1] < kBudget) {                    // tau < pts[0]
    a = 0.f; ga = fs; b = pts[0]; gb = s[1];
  } else if (s[kGrid] > kBudget) {         // tau > pts[last]
    a = pts[kGrid - 1]; ga = s[kGrid]; b = mx; gb = 0.f;
  } else {
#pragma unroll
    for (int i = 0; i < kGrid - 1; ++i) {
      if (s[i + 1] >= kBudget && s[i + 2] <= kBudget) {
        a = pts[i]; ga = s[i + 1]; b = pts[i + 1]; gb = s[i + 2];
        need_iter = false;
        break;
      }
    }
  }

  if (need_iter) {  // rare: Illinois false position on [a,b]
    int side = 0;
#pragma unroll 1
    for (int it = 0; it < kFallbackIters; ++it) {
      const float denom = gb - ga;
      float t = (denom != 0.f) ? b - (gb - kBudget) * (b - a) / denom
                               : 0.5f * (a + b);
      if (!(t > a && t < b)) t = 0.5f * (a + b);
      float s0 = 0.f, s1 = 0.f, s2 = 0.f, s3 = 0.f;
#pragma unroll
      for (int j = 0; j < VEC; ++j) {
        s0 += clip01(v[j].x - t);
        s1 += clip01(v[j].y - t);
        s2 += clip01(v[j].z - t);
        s3 += clip01(v[j].w - t);
      }
      float g = (s0 + s1) + (s2 + s3);
      waveReduceSumN<1>(&g);
      if (g > kBudget) {
        a = t; ga = g;
        if (side == 1) gb = kBudget + 0.5f * (gb - kBudget);
        side = 1;
      } else {
        b = t; gb = g;
        if (side == -1) ga = kBudget + 0.5f * (ga - kBudget);
        side = -1;
      }
    }
  }

  // False position within the (locally linear) segment.
  const float dd = ga - gb;
  float tau0 = (dd != 0.f) ? a + (ga - kBudget) * (b - a) / dd : 0.5f * (a + b);
  if (!(tau0 >= a && tau0 <= b)) tau0 = 0.5f * (a + b);

  // Newton correction: exact within the linear segment (matches reference).
  float gn[2] = {0.f, 0.f};  // gn[0]=g(tau0), gn[1]=n_active
#pragma unroll
  for (int j = 0; j < VEC; ++j) {
#pragma unroll
    for (int c = 0; c < 4; ++c) {
      const float t = v[j][c] - tau0;
      gn[0] += clip01(t);
      gn[1] += (t > 0.f && t < kPmax) ? 1.f : 0.f;
    }
  }
  waveReduceSumN<2>(gn);
  const float tau = tau0 + (gn[0] - kBudget) / fmaxf(gn[1], 1.0f);

#pragma unroll
  for (int j = 0; j < VEC; ++j) {
    fvec4 o;
#pragma unroll
    for (int c = 0; c < 4; ++c) o[c] = clip01(v[j][c] - tau);
    __builtin_nontemporal_store(o, &op[lane + 64 * j]);
  }
}

// Persistent waves + register double-buffer: while row r is reduced/solved/
// stored, the 16 global_load_dwordx4 for row r+W are already in flight into
// the other buffer, keeping HBM streaming through the ~4.6k-cycle compute.
//
// ROUND-1 LESSON: __launch_bounds__(256,2) only sets a MIN waves/EU; the
// allocator still targeted 4 waves/EU, capped VGPRs at 128 (=exactly the
// 4-wave cap; CSV VGPR_Count=128) and spilled the whole second buffer
// (WRITE_SIZE 249 MB vs 134 MB output). amdgpu_waves_per_eu(2,2) pins
// min=max=2 -> 256-VGPR cap, no occupancy incentive to spill. Live set:
// vA(64) + vB(64) + sums/addr ~= 170 regs.
__global__ __launch_bounds__(256)
__attribute__((amdgpu_waves_per_eu(2, 2))) void proj_kernel(
    const float* __restrict__ raw, float* __restrict__ out, int rows) {
  const int wave = threadIdx.x >> 6;
  const int lane = threadIdx.x & 63;
  const int W = gridDim.x * 4;  // total waves (one row per wave per step)
  int r = blockIdx.x * 4 + wave;
  if (r >= rows) return;

  fvec4 vA[VEC], vB[VEC];
  loadRow(raw, r, lane, vA);

  // Unroll-by-2 ping-pong so every buffer reference is a compile-time name
  // (runtime-indexed buffers would go to scratch — rule #20).
  while (true) {
    const int r1 = r + W;
    if (r1 < rows) loadRow(raw, r1, lane, vB);  // prefetch overlaps processRow
    processRow(vA, out, r, lane);
    if (r1 >= rows) return;

    const int r2 = r1 + W;
    if (r2 < rows) loadRow(raw, r2, lane, vA);
    processRow(vB, out, r1, lane);
    if (r2 >= rows) return;
    r = r2;
  }
}

extern "C" void kernel_launch(void* const* d_in, const int* in_sizes, int n_in,
                              void* d_out, int out_size, void* d_ws, size_t ws_size,
                              hipStream_t stream) {
  const float* raw = (const float*)d_in[0];
  float* out = (float*)d_out;
  const int rows = in_sizes[0] / NLINKS;
  // 2 blocks/CU * 256 CU = 512 persistent blocks (4 waves each = 2 waves/EU);
  // each wave grid-strides over rows with depth-1 register prefetch.
  int blocks = (rows + 3) / 4;
  if (blocks > 512) blocks = 512;
  hipLaunchKernelGGL(proj_kernel, dim3(blocks), dim3(256), 0, stream,
                     raw, out, rows);
}

// Round 3
// 241.318 us; speedup vs baseline: 1.0459x; 1.0459x over previous
//
#include <hip/hip_runtime.h>

#define NLINKS 4096
#define VEC 16            // fvec4 per lane: 16 * 4 * 64 lanes = 4096

typedef float fvec4 __attribute__((ext_vector_type(4)));

constexpr float kPmax = 0.1f;
constexpr float kBudget = 100.0f;
constexpr int kGrid = 8;          // fixed tau grid evaluated in the load pass
constexpr int kFallbackIters = 8; // Illinois iters when tau is outside the grid

// clip(x,0,PMAX) in ONE VALU op: v_med3_f32
__device__ __forceinline__ float clip01(float x) {
  return __builtin_amdgcn_fmed3f(x, 0.0f, kPmax);
}

// Batched reduce: N independent sums share interleaved shuffle latency.
template <int N>
__device__ __forceinline__ void waveReduceSumN(float* x) {
#pragma unroll
  for (int m = 32; m >= 1; m >>= 1) {
    float t[N];
#pragma unroll
    for (int k = 0; k < N; ++k) t[k] = __shfl_xor(x[k], m, 64);
#pragma unroll
    for (int k = 0; k < N; ++k) x[k] += t[k];
  }
}
__device__ __forceinline__ float waveReduceMax(float x) {
#pragma unroll
  for (int m = 32; m >= 1; m >>= 1) x = fmaxf(x, __shfl_xor(x, m, 64));
  return x;
}

// Async prefetch of one row into this wave's private LDS slot. Zero VGPR cost
// (no register round-trip) — this is the round-1/2 lesson: the allocator caps
// us at 128 VGPRs (VGPR_Count=128 + 115 MB scratch writes both rounds), so a
// register double-buffer ALWAYS spills. LDS dest is wave-uniform base +
// lane*16 (HW rule); per-lane global src rp + (lane+64j) fvec4s lands row
// element k at slot float k — linear, so readback mapping == old loadRow.
__device__ __forceinline__ void prefetchRow(const float* __restrict__ raw,
                                            int row, int lane, float* slot) {
  const float* rp = raw + (size_t)row * NLINKS;
#pragma unroll
  for (int j = 0; j < VEC; ++j) {
    __builtin_amdgcn_global_load_lds(
        (__attribute__((address_space(1))) void*)(rp + 4 * (lane + 64 * j)),
        (__attribute__((address_space(3))) void*)(slot + 256 * j),
        16, 0, 0);
  }
}

__device__ __forceinline__ void readRowLds(const float* slot, int lane,
                                           fvec4 (&v)[VEC]) {
  const fvec4* sp = (const fvec4*)slot;
#pragma unroll
  for (int j = 0; j < VEC; ++j) v[j] = sp[lane + 64 * j];  // ds_read_b128
}

// Per-row projection: identical arithmetic / op order to the 226 µs kernel
// (absmax must be unchanged). Only the scheduling around it changed.
__device__ __forceinline__ void processRow(const fvec4 (&v)[VEC],
                                           float* __restrict__ out, int row,
                                           int lane) {
  fvec4* op = (fvec4*)(out + (size_t)row * NLINKS);

  // tau grid: rows are ~N(0,1), n=4096 => tau ~= 0.641 +- 0.02. Grid spans
  // ~[-9sigma,+12sigma]; outside -> Illinois fallback (correct, ~never taken).
  const float pts[kGrid] = {0.45f, 0.52f, 0.58f, 0.62f, 0.66f, 0.70f, 0.78f, 0.90f};

  // Single pass: row max, g(0)=fs, and g(pts[i]) for all 8 grid points (ILP).
  float mx = -1e30f;
  float s[kGrid + 1];
#pragma unroll
  for (int k = 0; k <= kGrid; ++k) s[k] = 0.f;
#pragma unroll
  for (int j = 0; j < VEC; ++j) {
#pragma unroll
    for (int c = 0; c < 4; ++c) {
      const float x = v[j][c];
      mx = fmaxf(mx, x);
      s[0] += clip01(x);
#pragma unroll
      for (int i = 0; i < kGrid; ++i) s[i + 1] += clip01(x - pts[i]);
    }
  }
  waveReduceSumN<kGrid + 1>(s);
  mx = waveReduceMax(mx);
  const float fs = s[0];

  if (fs <= kBudget) {  // feasible: clip only (wave-uniform branch)
#pragma unroll
    for (int j = 0; j < VEC; ++j) {
      fvec4 o;
#pragma unroll
      for (int c = 0; c < 4; ++c) o[c] = clip01(v[j][c]);
      __builtin_nontemporal_store(o, &((fvec4*)op)[lane + 64 * j]);
    }
    return;
  }

  // Select bracketing segment. g is decreasing: g(0)=fs>B, g(mx)=0.
  float a = 0.f, ga = fs, b = mx, gb = 0.f;
  bool need_iter = true;
  if (s[1] < kBudget) {                    // tau < pts[0]
    a = 0.f; ga = fs; b = pts[0]; gb = s[1];
  } else if (s[kGrid] > kBudget) {         // tau > pts[last]
    a = pts[kGrid - 1]; ga = s[kGrid]; b = mx; gb = 0.f;
  } else {
#pragma unroll
    for (int i = 0; i < kGrid - 1; ++i) {
      if (s[i + 1] >= kBudget && s[i + 2] <= kBudget) {
        a = pts[i]; ga = s[i + 1]; b = pts[i + 1]; gb = s[i + 2];
        need_iter = false;
        break;
      }
    }
  }

  if (need_iter) {  // rare: Illinois false position on [a,b]
    int side = 0;
#pragma unroll 1
    for (int it = 0; it < kFallbackIters; ++it) {
      const float denom = gb - ga;
      float t = (denom != 0.f) ? b - (gb - kBudget) * (b - a) / denom
                               : 0.5f * (a + b);
      if (!(t > a && t < b)) t = 0.5f * (a + b);
      float s0 = 0.f, s1 = 0.f, s2 = 0.f, s3 = 0.f;
#pragma unroll
      for (int j = 0; j < VEC; ++j) {
        s0 += clip01(v[j].x - t);
        s1 += clip01(v[j].y - t);
        s2 += clip01(v[j].z - t);
        s3 += clip01(v[j].w - t);
      }
      float g = (s0 + s1) + (s2 + s3);
      waveReduceSumN<1>(&g);
      if (g > kBudget) {
        a = t; ga = g;
        if (side == 1) gb = kBudget + 0.5f * (gb - kBudget);
        side = 1;
      } else {
        b = t; gb = g;
        if (side == -1) ga = kBudget + 0.5f * (ga - kBudget);
        side = -1;
      }
    }
  }

  // False position within the (locally linear) segment.
  const float dd = ga - gb;
  float tau0 = (dd != 0.f) ? a + (ga - kBudget) * (b - a) / dd : 0.5f * (a + b);
  if (!(tau0 >= a && tau0 <= b)) tau0 = 0.5f * (a + b);

  // Newton correction: exact within the linear segment (matches reference).
  float gn[2] = {0.f, 0.f};  // gn[0]=g(tau0), gn[1]=n_active
#pragma unroll
  for (int j = 0; j < VEC; ++j) {
#pragma unroll
    for (int c = 0; c < 4; ++c) {
      const float t = v[j][c] - tau0;
      gn[0] += clip01(t);
      gn[1] += (t > 0.f && t < kPmax) ? 1.f : 0.f;
    }
  }
  waveReduceSumN<2>(gn);
  const float tau = tau0 + (gn[0] - kBudget) / fmaxf(gn[1], 1.0f);

#pragma unroll
  for (int j = 0; j < VEC; ++j) {
    fvec4 o;
#pragma unroll
    for (int c = 0; c < 4; ++c) o[c] = clip01(v[j][c] - tau);
    __builtin_nontemporal_store(o, &((fvec4*)op)[lane + 64 * j]);
  }
}

// Persistent waves + LDS prefetch pipeline. Per wave, steady state:
//   vmcnt(0)            -> prefetched row r is in my LDS slot
//   16x ds_read_b128    -> row r into registers
//   lgkmcnt(0)          -> slot free for reuse
//   prefetch row r+W    -> 16x global_load_lds, lands during compute
//   processRow + stores
// Waves never barrier (slots are wave-private). 4 waves x 16 KB = 64 KB/block
// -> LDS caps occupancy at 2 blocks/CU = 8 waves/CU; up to 128 KB of loads in
// flight per CU vs ~9 KB Little's-law minimum, so HBM streams through the
// ~4.6k-cycle compute phase instead of idling (the 57%-of-ceiling gap).
__global__ __launch_bounds__(256) void proj_kernel(
    const float* __restrict__ raw, float* __restrict__ out, int rows) {
  __shared__ float lds[4 * NLINKS];  // 64 KB: one 16 KB slot per wave
  const int wave = threadIdx.x >> 6;
  const int lane = threadIdx.x & 63;
  float* slot = lds + wave * NLINKS;
  const int W = gridDim.x * 4;  // total waves (one row per wave per step)
  int r = blockIdx.x * 4 + wave;
  if (r >= rows) return;

  prefetchRow(raw, r, lane, slot);

  fvec4 v[VEC];
  while (true) {
    // Drain the prefetch (also drains prior stores — waves are bandwidth-
    // oversubscribed 8x here, so the extra store-ack wait is noise).
    asm volatile("s_waitcnt vmcnt(0)" ::: "memory");
    readRowLds(slot, lane, v);
    // Slot must be fully read before the next prefetch may overwrite it.
    asm volatile("s_waitcnt lgkmcnt(0)" ::: "memory");

    const int rn = r + W;
    if (rn < rows) prefetchRow(raw, rn, lane, slot);  // overlaps processRow
    processRow(v, out, r, lane);
    if (rn >= rows) return;
    r = rn;
  }
}

extern "C" void kernel_launch(void* const* d_in, const int* in_sizes, int n_in,
                              void* d_out, int out_size, void* d_ws, size_t ws_size,
                              hipStream_t stream) {
  const float* raw = (const float*)d_in[0];
  float* out = (float*)d_out;
  const int rows = in_sizes[0] / NLINKS;
  // 2 blocks/CU * 256 CU = 512 persistent blocks (LDS-capped); each wave
  // grid-strides over rows with depth-1 LDS prefetch.
  int blocks = (rows + 3) / 4;
  if (blocks > 512) blocks = 512;
  hipLaunchKernelGGL(proj_kernel, dim3(blocks), dim3(256), 0, stream,
                     raw, out, rows);
}

// Round 4
// 240.523 us; speedup vs baseline: 1.0493x; 1.0033x over previous
//
#include <hip/hip_runtime.h>

#define NLINKS 4096
#define VEC 16            // fvec4 per lane: 16 * 4 * 64 lanes = 4096

typedef float fvec4 __attribute__((ext_vector_type(4)));

constexpr float kPmax = 0.1f;
constexpr float kBudget = 100.0f;
constexpr int kGrid = 8;          // fixed tau grid evaluated in the load pass
constexpr int kFallbackIters = 8; // Illinois iters when tau is outside the grid

// clip(x,0,PMAX) in ONE VALU op: v_med3_f32
__device__ __forceinline__ float clip01(float x) {
  return __builtin_amdgcn_fmed3f(x, 0.0f, kPmax);
}

// Batched reduce: N independent sums share interleaved shuffle latency.
template <int N>
__device__ __forceinline__ void waveReduceSumN(float* x) {
#pragma unroll
  for (int m = 32; m >= 1; m >>= 1) {
    float t[N];
#pragma unroll
    for (int k = 0; k < N; ++k) t[k] = __shfl_xor(x[k], m, 64);
#pragma unroll
    for (int k = 0; k < N; ++k) x[k] += t[k];
  }
}
__device__ __forceinline__ float waveReduceMax(float x) {
#pragma unroll
  for (int m = 32; m >= 1; m >>= 1) x = fmaxf(x, __shfl_xor(x, m, 64));
  return x;
}

// Async prefetch of one row into this wave's private LDS slot. Zero VGPR cost
// (no register round-trip) — round-1/2 lesson: the allocator caps us at 128
// VGPRs and a register double-buffer ALWAYS spills (WRITE_SIZE 249 MB).
// LDS dest is wave-uniform base + lane*16 (HW rule); per-lane global src
// rp + (lane+64j) fvec4s lands row element k at slot float k — linear, so
// readback mapping == the original register loadRow.
__device__ __forceinline__ void prefetchRow(const float* __restrict__ raw,
                                            int row, int lane, float* slot) {
  const float* rp = raw + (size_t)row * NLINKS;
#pragma unroll
  for (int j = 0; j < VEC; ++j) {
    __builtin_amdgcn_global_load_lds(
        (__attribute__((address_space(1))) void*)(rp + 4 * (lane + 64 * j)),
        (__attribute__((address_space(3))) void*)(slot + 256 * j),
        16, 0, 0);
  }
}

__device__ __forceinline__ void readRowLds(const float* slot, int lane,
                                           fvec4 (&v)[VEC]) {
  const fvec4* sp = (const fvec4*)slot;
#pragma unroll
  for (int j = 0; j < VEC; ++j) v[j] = sp[lane + 64 * j];  // ds_read_b128
}

// Per-row projection: identical arithmetic / op order to the 226 µs kernel
// (absmax must be unchanged). Only the scheduling around it changed.
__device__ __forceinline__ void processRow(const fvec4 (&v)[VEC],
                                           float* __restrict__ out, int row,
                                           int lane) {
  fvec4* op = (fvec4*)(out + (size_t)row * NLINKS);

  // tau grid: rows are ~N(0,1), n=4096 => tau ~= 0.641 +- 0.02. Grid spans
  // ~[-9sigma,+12sigma]; outside -> Illinois fallback (correct, ~never taken).
  const float pts[kGrid] = {0.45f, 0.52f, 0.58f, 0.62f, 0.66f, 0.70f, 0.78f, 0.90f};

  // Single pass: row max, g(0)=fs, and g(pts[i]) for all 8 grid points (ILP).
  float mx = -1e30f;
  float s[kGrid + 1];
#pragma unroll
  for (int k = 0; k <= kGrid; ++k) s[k] = 0.f;
#pragma unroll
  for (int j = 0; j < VEC; ++j) {
#pragma unroll
    for (int c = 0; c < 4; ++c) {
      const float x = v[j][c];
      mx = fmaxf(mx, x);
      s[0] += clip01(x);
#pragma unroll
      for (int i = 0; i < kGrid; ++i) s[i + 1] += clip01(x - pts[i]);
    }
  }
  waveReduceSumN<kGrid + 1>(s);
  mx = waveReduceMax(mx);
  const float fs = s[0];

  if (fs <= kBudget) {  // feasible: clip only (wave-uniform branch)
#pragma unroll
    for (int j = 0; j < VEC; ++j) {
      fvec4 o;
#pragma unroll
      for (int c = 0; c < 4; ++c) o[c] = clip01(v[j][c]);
      __builtin_nontemporal_store(o, &op[lane + 64 * j]);
    }
    return;
  }

  // Select bracketing segment. g is decreasing: g(0)=fs>B, g(mx)=0.
  float a = 0.f, ga = fs, b = mx, gb = 0.f;
  bool need_iter = true;
  if (s[1] < kBudget) {                    // tau < pts[0]
    a = 0.f; ga = fs; b = pts[0]; gb = s[1];
  } else if (s[kGrid] > kBudget) {         // tau > pts[last]
    a = pts[kGrid - 1]; ga = s[kGrid]; b = mx; gb = 0.f;
  } else {
#pragma unroll
    for (int i = 0; i < kGrid - 1; ++i) {
      if (s[i + 1] >= kBudget && s[i + 2] <= kBudget) {
        a = pts[i]; ga = s[i + 1]; b = pts[i + 1]; gb = s[i + 2];
        need_iter = false;
        break;
      }
    }
  }

  if (need_iter) {  // rare: Illinois false position on [a,b]
    int side = 0;
#pragma unroll 1
    for (int it = 0; it < kFallbackIters; ++it) {
      const float denom = gb - ga;
      float t = (denom != 0.f) ? b - (gb - kBudget) * (b - a) / denom
                               : 0.5f * (a + b);
      if (!(t > a && t < b)) t = 0.5f * (a + b);
      float s0 = 0.f, s1 = 0.f, s2 = 0.f, s3 = 0.f;
#pragma unroll
      for (int j = 0; j < VEC; ++j) {
        s0 += clip01(v[j].x - t);
        s1 += clip01(v[j].y - t);
        s2 += clip01(v[j].z - t);
        s3 += clip01(v[j].w - t);
      }
      float g = (s0 + s1) + (s2 + s3);
      waveReduceSumN<1>(&g);
      if (g > kBudget) {
        a = t; ga = g;
        if (side == 1) gb = kBudget + 0.5f * (gb - kBudget);
        side = 1;
      } else {
        b = t; gb = g;
        if (side == -1) ga = kBudget + 0.5f * (ga - kBudget);
        side = -1;
      }
    }
  }

  // False position within the (locally linear) segment.
  const float dd = ga - gb;
  float tau0 = (dd != 0.f) ? a + (ga - kBudget) * (b - a) / dd : 0.5f * (a + b);
  if (!(tau0 >= a && tau0 <= b)) tau0 = 0.5f * (a + b);

  // Newton correction: exact within the linear segment (matches reference).
  float gn[2] = {0.f, 0.f};  // gn[0]=g(tau0), gn[1]=n_active
#pragma unroll
  for (int j = 0; j < VEC; ++j) {
#pragma unroll
    for (int c = 0; c < 4; ++c) {
      const float t = v[j][c] - tau0;
      gn[0] += clip01(t);
      gn[1] += (t > 0.f && t < kPmax) ? 1.f : 0.f;
    }
  }
  waveReduceSumN<2>(gn);
  const float tau = tau0 + (gn[0] - kBudget) / fmaxf(gn[1], 1.0f);

#pragma unroll
  for (int j = 0; j < VEC; ++j) {
    fvec4 o;
#pragma unroll
    for (int c = 0; c < 4; ++c) o[c] = clip01(v[j][c] - tau);
    __builtin_nontemporal_store(o, &op[lane + 64 * j]);
  }
}

// Persistent waves + LDS prefetch pipeline, COUNTED waits (round-3 lesson).
//
// ROUND-3 POST-MORTEM: loop-top `vmcnt(0)` also drained the 16 nontemporal
// stores issued at the end of the previous processRow — vmcnt is ONE in-order
// counter covering loads AND stores on gfx9-lineage. That put a ~2-3k-cycle
// store drain on every iteration's critical path, cancelling the prefetch
// overlap (94 us ~= compute + store-drain per row, no overlap).
//
// FIX: per iteration the vm-op issue order is [16 prefetch loads][16 stores].
// `s_waitcnt vmcnt(16)` at the loop bottom completes exactly the 16 oldest
// ops (the prefetch) and leaves the stores draining in the background —
// never wait the counter to 0 in the main loop (T4).
__global__ __launch_bounds__(256) void proj_kernel(
    const float* __restrict__ raw, float* __restrict__ out, int rows) {
  __shared__ float lds[4 * NLINKS];  // 64 KB: one 16 KB slot per wave
  const int wave = threadIdx.x >> 6;
  const int lane = threadIdx.x & 63;
  float* slot = lds + wave * NLINKS;
  const int W = gridDim.x * 4;  // total waves (one row per wave per step)
  int r = blockIdx.x * 4 + wave;
  if (r >= rows) return;

  prefetchRow(raw, r, lane, slot);
  // Prologue only: no stores outstanding yet, so a full drain is exact.
  asm volatile("s_waitcnt vmcnt(0)" ::: "memory");

  fvec4 v[VEC];
  while (true) {
    readRowLds(slot, lane, v);
    // Slot must be fully read into regs before the next prefetch overwrites.
    asm volatile("s_waitcnt lgkmcnt(0)" ::: "memory");

    const int rn = r + W;
    if (rn < rows) prefetchRow(raw, rn, lane, slot);  // 16 loads, overlap
    processRow(v, out, r, lane);                      // ends with 16 stores
    if (rn >= rows) return;

    // Wait ONLY for the prefetch (oldest 16 vm-ops); let the 16 stores of
    // row r keep draining during the next iteration's compute.
    asm volatile("s_waitcnt vmcnt(16)" ::: "memory");
    r = rn;
  }
}

extern "C" void kernel_launch(void* const* d_in, const int* in_sizes, int n_in,
                              void* d_out, int out_size, void* d_ws, size_t ws_size,
                              hipStream_t stream) {
  const float* raw = (const float*)d_in[0];
  float* out = (float*)d_out;
  const int rows = in_sizes[0] / NLINKS;
  // 2 blocks/CU * 256 CU = 512 persistent blocks (LDS-capped); each wave
  // grid-strides over rows with depth-1 LDS prefetch.
  int blocks = (rows + 3) / 4;
  if (blocks > 512) blocks = 512;
  hipLaunchKernelGGL(proj_kernel, dim3(blocks), dim3(256), 0, stream,
                     raw, out, rows);
}